// Round 1
// baseline (139.627 us; speedup 1.0000x reference)
//
#include <hip/hip_runtime.h>
#include <stdint.h>

#define DIMC 512
#define INNER 512
#define NHEADS 8
#define DHEAD 64
#define NTOK 8192     // F*H*W = 8*32*32
#define NSEQ 8193     // +bos
#define MPAD 8320     // 65*128
#define QKV_COLS 1536

typedef __attribute__((ext_vector_type(8))) short bf16x8;
typedef __attribute__((ext_vector_type(4))) float f32x4;
typedef __attribute__((ext_vector_type(8))) unsigned short u16x8;

__device__ __forceinline__ float bf2f(unsigned short u) {
  return __uint_as_float(((unsigned int)u) << 16);
}
__device__ __forceinline__ unsigned short f2bf(float f) {
  unsigned int x = __float_as_uint(f);
  unsigned int lsb = (x >> 16) & 1u;
  x += 0x7fffu + lsb;           // round-to-nearest-even
  return (unsigned short)(x >> 16);
}

__device__ __forceinline__ void gload_lds16(const unsigned short* g, unsigned short* l) {
  __builtin_amdgcn_global_load_lds(
      (const __attribute__((address_space(1))) void*)g,
      (__attribute__((address_space(3))) void*)l, 16, 0, 0);
}

// ---------- conversions ----------
__global__ void k_conv_x(const float* __restrict__ x, unsigned short* __restrict__ xb) {
  int idx = (blockIdx.x * 256 + threadIdx.x) * 4;   // over MPAD*DIMC
  int row = idx / DIMC;
  ushort4 o;
  if (row < NSEQ) {
    const float4 v = *(const float4*)(x + idx);
    o.x = f2bf(v.x); o.y = f2bf(v.y); o.z = f2bf(v.z); o.w = f2bf(v.w);
  } else {
    o.x = 0; o.y = 0; o.z = 0; o.w = 0;
  }
  *(ushort4*)(xb + idx) = o;
}

__global__ void k_conv_w(const float* __restrict__ wq, const float* __restrict__ wkv,
                         const float* __restrict__ wout,
                         unsigned short* __restrict__ wqkvT,
                         unsigned short* __restrict__ woutT) {
  int idx = blockIdx.x * 256 + threadIdx.x;
  if (idx < QKV_COLS * DIMC) {
    int c = idx / DIMC, k = idx % DIMC;
    float v = (c < INNER) ? wq[k * INNER + c] * 0.125f      // fold q scale d^-0.5
                          : wkv[k * (2 * INNER) + (c - INNER)];
    wqkvT[idx] = f2bf(v);
  }
  if (idx < INNER * DIMC) {
    int c = idx / DIMC, k = idx % DIMC;
    woutT[idx] = f2bf(wout[k * DIMC + c]);
  }
}

// ---------- GEMM: C[M x N] = A[M x 512] * B[512 x N], BT given N x 512 ----------
template <int LDC, bool OUT_BF16>
__global__ __launch_bounds__(256)
void k_gemm(const unsigned short* __restrict__ A,
            const unsigned short* __restrict__ BT,
            void* __restrict__ C,
            const float* __restrict__ bias,
            int Mreal) {
  __shared__ unsigned short As[128 * 32];
  __shared__ unsigned short Bs[128 * 32];
  const int tm = blockIdx.x;
  const int tn = blockIdx.y;
  const int tid = (int)threadIdx.x;
  const int wave = tid >> 6;
  const int lane = tid & 63;
  const int wm = (wave >> 1) * 64;
  const int wn = (wave & 1) * 64;

  f32x4 acc[4][4];
#pragma unroll
  for (int m = 0; m < 4; ++m)
#pragma unroll
    for (int n = 0; n < 4; ++n) {
      acc[m][n][0] = 0.f; acc[m][n][1] = 0.f; acc[m][n][2] = 0.f; acc[m][n][3] = 0.f;
    }

  const size_t a_base = (size_t)tm * 128 * DIMC;
  const size_t b_base = (size_t)tn * 128 * DIMC;
  const int lrow = lane >> 2;        // 0..15
  const int lk = (lane & 3) * 8;     // 0,8,16,24

  for (int k0 = 0; k0 < DIMC; k0 += 32) {
    __syncthreads();   // previous tile fully consumed
#pragma unroll
    for (int c = 0; c < 2; ++c) {
      const int rA = wave * 32 + c * 16;           // wave-uniform
      gload_lds16(A + a_base + (size_t)(rA + lrow) * DIMC + k0 + lk, &As[rA * 32]);
      gload_lds16(BT + b_base + (size_t)(rA + lrow) * DIMC + k0 + lk, &Bs[rA * 32]);
    }
    __syncthreads();   // data ready (compiler drains vmcnt before barrier)

    const int fr = lane & 15;
    const int kg = (lane >> 4) * 8;
    bf16x8 af[4], bfr[4];
#pragma unroll
    for (int m = 0; m < 4; ++m)
      af[m] = *(const bf16x8*)&As[(wm + m * 16 + fr) * 32 + kg];
#pragma unroll
    for (int n = 0; n < 4; ++n)
      bfr[n] = *(const bf16x8*)&Bs[(wn + n * 16 + fr) * 32 + kg];
#pragma unroll
    for (int m = 0; m < 4; ++m)
#pragma unroll
      for (int n = 0; n < 4; ++n)
        acc[m][n] = __builtin_amdgcn_mfma_f32_16x16x32_bf16(af[m], bfr[n], acc[m][n], 0, 0, 0);
  }

  // epilogue: D col = lane&15, row = (lane>>4)*4 + reg   [m89/m91 verified]
  const int fr = lane & 15;
  const int rg = (lane >> 4) * 4;
#pragma unroll
  for (int m = 0; m < 4; ++m) {
#pragma unroll
    for (int r = 0; r < 4; ++r) {
      const int row = tm * 128 + wm + m * 16 + rg + r;
      if (row < Mreal) {
#pragma unroll
        for (int n = 0; n < 4; ++n) {
          const int col = tn * 128 + wn + n * 16 + fr;
          const float v = acc[m][n][r];
          if constexpr (OUT_BF16) {
            ((unsigned short*)C)[(size_t)row * LDC + col] = f2bf(v);
          } else {
            ((float*)C)[(size_t)row * LDC + col] = v + bias[col];
          }
        }
      }
    }
  }
}

// ---------- attention: one block per token ----------
__global__ __launch_bounds__(256)
void k_attn(const unsigned short* __restrict__ qkv, const float* __restrict__ w_th,
            unsigned short* __restrict__ Ob) {
  __shared__ float q_s[512];
  __shared__ float sim[8][28];
  __shared__ float mixed[8][28];
  __shared__ int nbr[27];
  __shared__ float wth_s[64];

  const int bid = (int)blockIdx.x;
  const int i = ((bid & 7) << 10) | (bid >> 3);   // XCD swizzle, 8192 = 8*1024
  const int t = (int)threadIdx.x;

  // phase 0: stage q (row i+1), w_th, neighbor tokens
  {
    const size_t qrow = (size_t)(i + 1) * QKV_COLS;
    q_s[t]       = bf2f(qkv[qrow + t]);
    q_s[t + 256] = bf2f(qkv[qrow + t + 256]);
  }
  if (t < 64) wth_s[t] = w_th[t];
  if (t < 27) {
    const int f = i >> 10, r = i & 1023, y = r >> 5, xx = r & 31;
    const int a = t / 9, rem = t % 9, bb = rem / 3, cc = rem % 3;
    const int sf = f + a - 1, sy = y + bb - 1, sx = xx + cc - 1;
    int tok = -1;
    if (sf >= 0 && sf < 8 && sy >= 0 && sy < 32 && sx >= 0 && sx < 32) {
      const int tk = (sf << 10) | (sy << 5) | sx;
      if (tk <= i) tok = tk;      // causal: attend iff source index <= i
    }
    nbr[t] = tok;
  }
  __syncthreads();

  // phase 1: sim[h][jj], jj=0 is BOS
  if (t < 224) {
    const int h = t / 28, jj = t % 28;
    float s;
    int src = 0;
    bool valid = true;
    if (jj > 0) {
      const int tok = nbr[jj - 1];
      if (tok < 0) valid = false; else src = tok + 1;
    }
    if (valid) {
      const unsigned short* kp = qkv + (size_t)src * QKV_COLS + INNER + h * DHEAD;
      const float* qp = q_s + h * DHEAD;
      s = 0.f;
#pragma unroll
      for (int u = 0; u < 8; ++u) {
        const u16x8 kv = *(const u16x8*)(kp + u * 8);
#pragma unroll
        for (int e = 0; e < 8; ++e) s += qp[u * 8 + e] * bf2f(kv[e]);
      }
    } else {
      s = -1e30f;
    }
    sim[h][jj] = s;
  }
  __syncthreads();

  // phase 2: softmax per head (8 threads, 28-wide rows)
  if (t < 8) {
    float mx = -1e30f;
#pragma unroll
    for (int j = 0; j < 28; ++j) mx = fmaxf(mx, sim[t][j]);
    float e[28]; float sum = 0.f;
#pragma unroll
    for (int j = 0; j < 28; ++j) { e[j] = __expf(sim[t][j] - mx); sum += e[j]; }
    const float inv = 1.0f / sum;
#pragma unroll
    for (int j = 0; j < 28; ++j) sim[t][j] = e[j] * inv;
  }
  __syncthreads();

  // phase 3: talking heads  mixed[g][j] = sum_h w_th[g,h] * attn[h][j]
  if (t < 224) {
    const int g = t / 28, jj = t % 28;
    float s = 0.f;
#pragma unroll
    for (int h = 0; h < 8; ++h) s += wth_s[g * 8 + h] * sim[h][jj];
    mixed[g][jj] = s;
  }
  __syncthreads();

  // phase 4: PV — thread handles (g,d) pairs t and t+256
#pragma unroll
  for (int p = 0; p < 2; ++p) {
    const int gd = t + p * 256;
    const int g = gd >> 6, d = gd & 63;
    const unsigned short* vbase = qkv + 2 * INNER + g * DHEAD + d;
    float acc = mixed[g][0] * bf2f(vbase[0]);     // BOS (row 0)
#pragma unroll
    for (int jj = 1; jj < 28; ++jj) {
      const int tok = nbr[jj - 1];
      if (tok >= 0) acc += mixed[g][jj] * bf2f(vbase[(size_t)(tok + 1) * QKV_COLS]);
    }
    Ob[(size_t)(i + 1) * INNER + gd] = f2bf(acc);
  }
}

// ---------- BOS output row: O[0] = v[token0] ----------
__global__ void k_bos(const unsigned short* __restrict__ qkv, unsigned short* __restrict__ Ob) {
  const int t = (int)(blockIdx.x * 256 + threadIdx.x);
  if (t < INNER) Ob[t] = qkv[2 * INNER + t];
}

extern "C" void kernel_launch(void* const* d_in, const int* in_sizes, int n_in,
                              void* d_out, int out_size, void* d_ws, size_t ws_size,
                              hipStream_t stream) {
  (void)in_sizes; (void)n_in; (void)out_size; (void)ws_size;
  const float* x     = (const float*)d_in[0];
  const float* w_q   = (const float*)d_in[1];
  const float* w_kv  = (const float*)d_in[2];
  const float* w_th  = (const float*)d_in[3];
  const float* w_out = (const float*)d_in[4];
  const float* b_out = (const float*)d_in[5];
  float* out = (float*)d_out;

  char* ws = (char*)d_ws;
  unsigned short* xb    = (unsigned short*)ws;                       // MPAD*512 bf16 (reused as Ob)
  unsigned short* wqkvT = (unsigned short*)(ws + 8519680);           // 1536*512 bf16
  unsigned short* woutT = (unsigned short*)(ws + 8519680 + 1572864); // 512*512 bf16
  unsigned short* qkvb  = (unsigned short*)(ws + 8519680 + 1572864 + 524288); // 8193*1536 bf16

  // 1) conversions
  k_conv_x<<<(MPAD * DIMC) / (256 * 4), 256, 0, stream>>>(x, xb);
  k_conv_w<<<(QKV_COLS * DIMC) / 256, 256, 0, stream>>>(w_q, w_kv, w_out, wqkvT, woutT);
  // 2) qkv = xb @ [w_q*0.125 | w_kv]
  k_gemm<QKV_COLS, true><<<dim3(MPAD / 128, QKV_COLS / 128), 256, 0, stream>>>(
      xb, wqkvT, qkvb, nullptr, NSEQ);
  // 3) sparse attention (writes Ob rows 1..8192; Ob aliases xb which is now dead)
  k_attn<<<NTOK, 256, 0, stream>>>(qkvb, w_th, xb);
  k_bos<<<2, 256, 0, stream>>>(qkvb, xb);
  // 4) out = Ob @ w_out + b_out
  k_gemm<DIMC, false><<<dim3(MPAD / 128, DIMC / 128), 256, 0, stream>>>(
      xb, woutT, out, b_out, NSEQ);
}

// Round 2
// 89.569 us; speedup vs baseline: 1.5589x; 1.5589x over previous
//
#include <hip/hip_runtime.h>
#include <stdint.h>

#define DIMC 512
#define INNER 512
#define NHEADS 8
#define DHEAD 64
#define NTOK 8192     // F*H*W = 8*32*32
#define NSEQ 8193     // +bos
#define MPAD 8320     // 65*128
#define QKV_COLS 1536

typedef __attribute__((ext_vector_type(8))) short bf16x8;
typedef __attribute__((ext_vector_type(4))) float f32x4;
typedef __attribute__((ext_vector_type(8))) unsigned short u16x8;

__device__ __forceinline__ float bf2f(unsigned short u) {
  return __uint_as_float(((unsigned int)u) << 16);
}
__device__ __forceinline__ unsigned short f2bf(float f) {
  unsigned int x = __float_as_uint(f);
  unsigned int lsb = (x >> 16) & 1u;
  x += 0x7fffu + lsb;           // round-to-nearest-even
  return (unsigned short)(x >> 16);
}

__device__ __forceinline__ void gload_lds16(const unsigned short* g, unsigned short* l) {
  __builtin_amdgcn_global_load_lds(
      (const __attribute__((address_space(1))) void*)g,
      (__attribute__((address_space(3))) void*)l, 16, 0, 0);
}

// ---------- conversions ----------
__global__ void k_conv_x(const float* __restrict__ x, unsigned short* __restrict__ xb) {
  int idx = (blockIdx.x * 256 + threadIdx.x) * 4;   // over MPAD*DIMC
  int row = idx / DIMC;
  ushort4 o;
  if (row < NSEQ) {
    const float4 v = *(const float4*)(x + idx);
    o.x = f2bf(v.x); o.y = f2bf(v.y); o.z = f2bf(v.z); o.w = f2bf(v.w);
  } else {
    o.x = 0; o.y = 0; o.z = 0; o.w = 0;
  }
  *(ushort4*)(xb + idx) = o;
}

__global__ void k_conv_w(const float* __restrict__ wq, const float* __restrict__ wkv,
                         const float* __restrict__ wout,
                         unsigned short* __restrict__ wqkvT,
                         unsigned short* __restrict__ woutT) {
  int idx = blockIdx.x * 256 + threadIdx.x;
  if (idx < QKV_COLS * DIMC) {
    int c = idx / DIMC, k = idx % DIMC;
    float v = (c < INNER) ? wq[k * INNER + c] * 0.125f      // fold q scale d^-0.5
                          : wkv[k * (2 * INNER) + (c - INNER)];
    wqkvT[idx] = f2bf(v);
  }
  if (idx < INNER * DIMC) {
    int c = idx / DIMC, k = idx % DIMC;
    woutT[idx] = f2bf(wout[k * DIMC + c]);
  }
}

// ---------- GEMM: C[M x N] = A[M x 512] * B[512 x N], BT given N x 512 ----------
template <int LDC, bool OUT_BF16>
__global__ __launch_bounds__(256)
void k_gemm(const unsigned short* __restrict__ A,
            const unsigned short* __restrict__ BT,
            void* __restrict__ C,
            const float* __restrict__ bias,
            int Mreal) {
  __shared__ unsigned short As[128 * 32];
  __shared__ unsigned short Bs[128 * 32];
  const int tm = blockIdx.x;
  const int tn = blockIdx.y;
  const int tid = (int)threadIdx.x;
  const int wave = tid >> 6;
  const int lane = tid & 63;
  const int wm = (wave >> 1) * 64;
  const int wn = (wave & 1) * 64;

  f32x4 acc[4][4];
#pragma unroll
  for (int m = 0; m < 4; ++m)
#pragma unroll
    for (int n = 0; n < 4; ++n) {
      acc[m][n][0] = 0.f; acc[m][n][1] = 0.f; acc[m][n][2] = 0.f; acc[m][n][3] = 0.f;
    }

  const size_t a_base = (size_t)tm * 128 * DIMC;
  const size_t b_base = (size_t)tn * 128 * DIMC;
  const int lrow = lane >> 2;        // 0..15
  const int lk = (lane & 3) * 8;     // 0,8,16,24

  for (int k0 = 0; k0 < DIMC; k0 += 32) {
    __syncthreads();   // previous tile fully consumed
#pragma unroll
    for (int c = 0; c < 2; ++c) {
      const int rA = wave * 32 + c * 16;           // wave-uniform
      gload_lds16(A + a_base + (size_t)(rA + lrow) * DIMC + k0 + lk, &As[rA * 32]);
      gload_lds16(BT + b_base + (size_t)(rA + lrow) * DIMC + k0 + lk, &Bs[rA * 32]);
    }
    __syncthreads();   // data ready (compiler drains vmcnt before barrier)

    const int fr = lane & 15;
    const int kg = (lane >> 4) * 8;
    bf16x8 af[4], bfr[4];
#pragma unroll
    for (int m = 0; m < 4; ++m)
      af[m] = *(const bf16x8*)&As[(wm + m * 16 + fr) * 32 + kg];
#pragma unroll
    for (int n = 0; n < 4; ++n)
      bfr[n] = *(const bf16x8*)&Bs[(wn + n * 16 + fr) * 32 + kg];
#pragma unroll
    for (int m = 0; m < 4; ++m)
#pragma unroll
      for (int n = 0; n < 4; ++n)
        acc[m][n] = __builtin_amdgcn_mfma_f32_16x16x32_bf16(af[m], bfr[n], acc[m][n], 0, 0, 0);
  }

  // epilogue: D col = lane&15, row = (lane>>4)*4 + reg   [m89/m91 verified]
  const int fr = lane & 15;
  const int rg = (lane >> 4) * 4;
#pragma unroll
  for (int m = 0; m < 4; ++m) {
#pragma unroll
    for (int r = 0; r < 4; ++r) {
      const int row = tm * 128 + wm + m * 16 + rg + r;
      if (row < Mreal) {
#pragma unroll
        for (int n = 0; n < 4; ++n) {
          const int col = tn * 128 + wn + n * 16 + fr;
          const float v = acc[m][n][r];
          if constexpr (OUT_BF16) {
            ((unsigned short*)C)[(size_t)row * LDC + col] = f2bf(v);
          } else {
            ((float*)C)[(size_t)row * LDC + col] = v + bias[col];
          }
        }
      }
    }
  }
}

// ---------- attention: one WAVE per token, no LDS, no block barriers ----------
__global__ __launch_bounds__(256)
void k_attn2(const unsigned short* __restrict__ qkv, const float* __restrict__ w_th,
             unsigned short* __restrict__ Ob) {
  const int bid = (int)blockIdx.x;
  const int blk = ((bid & 7) << 8) | (bid >> 3);   // XCD swizzle: 2048 = 8*256
  const int t = (int)threadIdx.x;
  const int w = t >> 6;
  const int l = t & 63;
  const int i = blk * 4 + w;                        // token 0..8191
  const int e = l & 7;                              // element-group within head
  const int gbase = l & 56;                         // h*8

  // lane l (<27) computes neighbor source token for nIdx = l
  int my_nbr = -1;
  {
    const int f = i >> 10, r = i & 1023, y = r >> 5, xx = r & 31;
    const int a = l / 9, rem = l % 9, bb = rem / 3, cc = rem % 3;
    const int sf = f + a - 1, sy = y + bb - 1, sx = xx + cc - 1;
    if (l < 27 && (unsigned)sf < 8u && (unsigned)sy < 32u && (unsigned)sx < 32u) {
      const int tk = (sf << 10) | (sy << 5) | sx;
      if (tk <= i) my_nbr = tk;                     // causal
    }
  }

  // q fragment: head h = l>>3, dims e*8..e*8+7  (scale folded into w_q)
  const size_t qrow = (size_t)(i + 1) * QKV_COLS;
  float qf[8];
  {
    const u16x8 q8 = *(const u16x8*)(qkv + qrow + l * 8);
#pragma unroll
    for (int u = 0; u < 8; ++u) qf[u] = bf2f(q8[u]);
  }

  // ---- sim: s[p] = sim[h][8p+e] ----
  float s[4] = {-1e30f, -1e30f, -1e30f, -1e30f};
  {  // j = 0: BOS, row 0, never masked
    const u16x8 k8 = *(const u16x8*)(qkv + INNER + l * 8);
    float p = 0.f;
#pragma unroll
    for (int u = 0; u < 8; ++u) p = fmaf(qf[u], bf2f(k8[u]), p);
    p += __shfl_xor(p, 1); p += __shfl_xor(p, 2); p += __shfl_xor(p, 4);
    if (e == 0) s[0] = p;
  }
#pragma unroll
  for (int j = 1; j < 28; ++j) {
    const int tok = __shfl(my_nbr, j - 1);          // wave-uniform
    if (tok >= 0) {
      const u16x8 k8 = *(const u16x8*)(qkv + (size_t)(tok + 1) * QKV_COLS + INNER + l * 8);
      float p = 0.f;
#pragma unroll
      for (int u = 0; u < 8; ++u) p = fmaf(qf[u], bf2f(k8[u]), p);
      p += __shfl_xor(p, 1); p += __shfl_xor(p, 2); p += __shfl_xor(p, 4);
      if (e == (j & 7)) s[j >> 3] = p;
    }
  }

  // ---- softmax over 28 entries spread across 8 lanes x 4 regs ----
  float mx = fmaxf(fmaxf(s[0], s[1]), fmaxf(s[2], s[3]));
  mx = fmaxf(mx, __shfl_xor(mx, 1));
  mx = fmaxf(mx, __shfl_xor(mx, 2));
  mx = fmaxf(mx, __shfl_xor(mx, 4));
  float a4[4]; float sum = 0.f;
#pragma unroll
  for (int p = 0; p < 4; ++p) { a4[p] = __expf(s[p] - mx); sum += a4[p]; }
  sum += __shfl_xor(sum, 1); sum += __shfl_xor(sum, 2); sum += __shfl_xor(sum, 4);
  const float inv = 1.0f / sum;
#pragma unroll
  for (int p = 0; p < 4; ++p) a4[p] *= inv;

  // ---- talking heads: m[p] = mixed[h][8p+e] = sum_h2 wth[h][h2]*attn[h2][8p+e] ----
  float wth[8];
  {
    const float4 w0 = *(const float4*)(w_th + gbase);
    const float4 w1 = *(const float4*)(w_th + gbase + 4);
    wth[0] = w0.x; wth[1] = w0.y; wth[2] = w0.z; wth[3] = w0.w;
    wth[4] = w1.x; wth[5] = w1.y; wth[6] = w1.z; wth[7] = w1.w;
  }
  float m4[4];
#pragma unroll
  for (int p = 0; p < 4; ++p) {
    float acc = 0.f;
#pragma unroll
    for (int h2 = 0; h2 < 8; ++h2)
      acc = fmaf(wth[h2], __shfl(a4[p], (h2 << 3) | e), acc);
    m4[p] = acc;
  }

  // ---- PV: acc8[u] = out[h][e*8+u] ----
  float acc8[8] = {0.f, 0.f, 0.f, 0.f, 0.f, 0.f, 0.f, 0.f};
  {  // BOS
    const float mv = __shfl(m4[0], gbase);
    const u16x8 v8 = *(const u16x8*)(qkv + 2 * INNER + l * 8);
#pragma unroll
    for (int u = 0; u < 8; ++u) acc8[u] = fmaf(mv, bf2f(v8[u]), acc8[u]);
  }
#pragma unroll
  for (int j = 1; j < 28; ++j) {
    const int tok = __shfl(my_nbr, j - 1);
    if (tok >= 0) {
      const float mv = __shfl(m4[j >> 3], gbase | (j & 7));
      const u16x8 v8 = *(const u16x8*)(qkv + (size_t)(tok + 1) * QKV_COLS + 2 * INNER + l * 8);
#pragma unroll
      for (int u = 0; u < 8; ++u) acc8[u] = fmaf(mv, bf2f(v8[u]), acc8[u]);
    }
  }

  // store 16B coalesced
  u16x8 o;
#pragma unroll
  for (int u = 0; u < 8; ++u) o[u] = f2bf(acc8[u]);
  *(u16x8*)(Ob + (size_t)(i + 1) * INNER + l * 8) = o;
}

// ---------- BOS output row: O[0] = v[token0] ----------
__global__ void k_bos(const unsigned short* __restrict__ qkv, unsigned short* __restrict__ Ob) {
  const int t = (int)(blockIdx.x * 256 + threadIdx.x);
  if (t < INNER) Ob[t] = qkv[2 * INNER + t];
}

extern "C" void kernel_launch(void* const* d_in, const int* in_sizes, int n_in,
                              void* d_out, int out_size, void* d_ws, size_t ws_size,
                              hipStream_t stream) {
  (void)in_sizes; (void)n_in; (void)out_size; (void)ws_size;
  const float* x     = (const float*)d_in[0];
  const float* w_q   = (const float*)d_in[1];
  const float* w_kv  = (const float*)d_in[2];
  const float* w_th  = (const float*)d_in[3];
  const float* w_out = (const float*)d_in[4];
  const float* b_out = (const float*)d_in[5];
  float* out = (float*)d_out;

  char* ws = (char*)d_ws;
  unsigned short* xb    = (unsigned short*)ws;                       // MPAD*512 bf16 (reused as Ob)
  unsigned short* wqkvT = (unsigned short*)(ws + 8519680);           // 1536*512 bf16
  unsigned short* woutT = (unsigned short*)(ws + 8519680 + 1572864); // 512*512 bf16
  unsigned short* qkvb  = (unsigned short*)(ws + 8519680 + 1572864 + 524288); // 8193*1536 bf16

  // 1) conversions
  k_conv_x<<<(MPAD * DIMC) / (256 * 4), 256, 0, stream>>>(x, xb);
  k_conv_w<<<(QKV_COLS * DIMC) / 256, 256, 0, stream>>>(w_q, w_kv, w_out, wqkvT, woutT);
  // 2) qkv = xb @ [w_q*0.125 | w_kv]
  k_gemm<QKV_COLS, true><<<dim3(MPAD / 128, QKV_COLS / 128), 256, 0, stream>>>(
      xb, wqkvT, qkvb, nullptr, NSEQ);
  // 3) sparse attention: one wave per token (writes Ob rows 1..8192; Ob aliases xb)
  k_attn2<<<NTOK / 4, 256, 0, stream>>>(qkvb, w_th, xb);
  k_bos<<<2, 256, 0, stream>>>(qkvb, xb);
  // 4) out = Ob @ w_out + b_out
  k_gemm<DIMC, false><<<dim3(MPAD / 128, DIMC / 128), 256, 0, stream>>>(
      xb, woutT, out, b_out, NSEQ);
}

// Round 4
// 84.934 us; speedup vs baseline: 1.6439x; 1.0546x over previous
//
#include <hip/hip_runtime.h>
#include <stdint.h>

#define DIMC 512
#define INNER 512
#define NHEADS 8
#define DHEAD 64
#define NTOK 8192     // F*H*W = 8*32*32
#define NSEQ 8193     // +bos
#define MPAD 8320     // 65*128
#define QKV_COLS 1536

#define CONV_XT   (MPAD * DIMC / 4)
#define CONV_WQKV (QKV_COLS * DIMC)
#define CONV_WOUT (INNER * DIMC)
#define CONV_TOT  (CONV_XT + CONV_WQKV + CONV_WOUT)   // 2,113,536 = 8256*256

typedef __attribute__((ext_vector_type(8))) short bf16x8;
typedef __attribute__((ext_vector_type(4))) float f32x4;
typedef __attribute__((ext_vector_type(8))) unsigned short u16x8;

__device__ __forceinline__ float bf2f(unsigned short u) {
  return __uint_as_float(((unsigned int)u) << 16);
}
__device__ __forceinline__ unsigned short f2bf(float f) {
  unsigned int x = __float_as_uint(f);
  unsigned int lsb = (x >> 16) & 1u;
  x += 0x7fffu + lsb;           // round-to-nearest-even
  return (unsigned short)(x >> 16);
}

__device__ __forceinline__ void gload_lds16(const unsigned short* g, unsigned short* l) {
  __builtin_amdgcn_global_load_lds(
      (const __attribute__((address_space(1))) void*)g,
      (__attribute__((address_space(3))) void*)l, 16, 0, 0);
}

// ---------- fused conversions: x -> bf16 (padded), weights -> bf16 transposed ----------
__global__ void k_conv(const float* __restrict__ x, const float* __restrict__ wq,
                       const float* __restrict__ wkv, const float* __restrict__ wout,
                       unsigned short* __restrict__ xb, unsigned short* __restrict__ wqkvT,
                       unsigned short* __restrict__ woutT) {
  const int gid = blockIdx.x * 256 + threadIdx.x;
  if (gid < CONV_XT) {
    const int idx = gid * 4;
    const int row = idx / DIMC;
    ushort4 o;
    if (row < NSEQ) {
      const float4 v = *(const float4*)(x + idx);
      o.x = f2bf(v.x); o.y = f2bf(v.y); o.z = f2bf(v.z); o.w = f2bf(v.w);
    } else {
      o.x = 0; o.y = 0; o.z = 0; o.w = 0;
    }
    *(ushort4*)(xb + idx) = o;
  } else if (gid < CONV_XT + CONV_WQKV) {
    const int idx = gid - CONV_XT;
    const int c = idx / DIMC, k = idx % DIMC;
    const float v = (c < INNER) ? wq[k * INNER + c] * 0.125f   // fold q scale d^-0.5
                                : wkv[k * (2 * INNER) + (c - INNER)];
    wqkvT[idx] = f2bf(v);
  } else {
    const int idx = gid - CONV_XT - CONV_WQKV;
    const int c = idx / DIMC, k = idx % DIMC;
    woutT[idx] = f2bf(wout[k * DIMC + c]);
  }
}

// ---------- GEMM: C[M x N] = A[M x 512] * B[512 x N], BT given N x 512 ----------
// 128x128 tile, BK=64 (8 K-steps, halved barrier drains vs BK=32).
template <int LDC, bool OUT_BF16>
__global__ __launch_bounds__(256)
void k_gemm(const unsigned short* __restrict__ A,
            const unsigned short* __restrict__ BT,
            void* __restrict__ C,
            const float* __restrict__ bias,
            int Mreal) {
  __shared__ unsigned short As[128 * 64];
  __shared__ unsigned short Bs[128 * 64];
  const int tm = blockIdx.x;
  const int tn = blockIdx.y;
  const int tid = (int)threadIdx.x;
  const int wave = tid >> 6;
  const int lane = tid & 63;
  const int wm = (wave >> 1) * 64;
  const int wn = (wave & 1) * 64;

  f32x4 acc[4][4];
#pragma unroll
  for (int m = 0; m < 4; ++m)
#pragma unroll
    for (int n = 0; n < 4; ++n) {
      acc[m][n][0] = 0.f; acc[m][n][1] = 0.f; acc[m][n][2] = 0.f; acc[m][n][3] = 0.f;
    }

  const size_t a_base = (size_t)tm * 128 * DIMC;
  const size_t b_base = (size_t)tn * 128 * DIMC;
  const int lrow = lane >> 3;        // 0..7
  const int lk = (lane & 7) * 8;     // 0..56 shorts (16B units)

  for (int k0 = 0; k0 < DIMC; k0 += 64) {
    __syncthreads();   // previous tile fully consumed
#pragma unroll
    for (int c = 0; c < 4; ++c) {
      const int rA = wave * 32 + c * 8;            // wave-uniform
      gload_lds16(A + a_base + (size_t)(rA + lrow) * DIMC + k0 + lk, &As[rA * 64]);
      gload_lds16(BT + b_base + (size_t)(rA + lrow) * DIMC + k0 + lk, &Bs[rA * 64]);
    }
    __syncthreads();   // data ready (compiler drains vmcnt before barrier)

    const int fr = lane & 15;
    const int kg = (lane >> 4) * 8;
#pragma unroll
    for (int kk = 0; kk < 2; ++kk) {               // two K=32 sub-phases
      bf16x8 af[4], bfr[4];
#pragma unroll
      for (int m = 0; m < 4; ++m)
        af[m] = *(const bf16x8*)&As[(wm + m * 16 + fr) * 64 + kk * 32 + kg];
#pragma unroll
      for (int n = 0; n < 4; ++n)
        bfr[n] = *(const bf16x8*)&Bs[(wn + n * 16 + fr) * 64 + kk * 32 + kg];
#pragma unroll
      for (int m = 0; m < 4; ++m)
#pragma unroll
        for (int n = 0; n < 4; ++n)
          acc[m][n] = __builtin_amdgcn_mfma_f32_16x16x32_bf16(af[m], bfr[n], acc[m][n], 0, 0, 0);
    }
  }

  // epilogue: D col = lane&15, row = (lane>>4)*4 + reg   [m89/m91 verified]
  const int fr = lane & 15;
  const int rg = (lane >> 4) * 4;
#pragma unroll
  for (int m = 0; m < 4; ++m) {
#pragma unroll
    for (int r = 0; r < 4; ++r) {
      const int row = tm * 128 + wm + m * 16 + rg + r;
      if (row < Mreal) {
#pragma unroll
        for (int n = 0; n < 4; ++n) {
          const int col = tn * 128 + wn + n * 16 + fr;
          const float v = acc[m][n][r];
          if constexpr (OUT_BF16) {
            ((unsigned short*)C)[(size_t)row * LDC + col] = f2bf(v);
          } else {
            ((float*)C)[(size_t)row * LDC + col] = v + bias[col];
          }
        }
      }
    }
  }
}

// ---------- attention: one WAVE per token, no LDS, no block barriers ----------
__global__ __launch_bounds__(256)
void k_attn2(const unsigned short* __restrict__ qkv, const float* __restrict__ w_th,
             unsigned short* __restrict__ Ob) {
  const int bid = (int)blockIdx.x;
  const int blk = ((bid & 7) << 8) | (bid >> 3);   // XCD swizzle: 2048 = 8*256
  const int t = (int)threadIdx.x;
  const int w = t >> 6;
  const int l = t & 63;
  const int i = blk * 4 + w;                        // token 0..8191
  const int e = l & 7;                              // element-group within head
  const int gbase = l & 56;                         // h*8

  // lane l (<27) computes neighbor source token for nIdx = l
  int my_nbr = -1;
  {
    const int f = i >> 10, r = i & 1023, y = r >> 5, xx = r & 31;
    const int a = l / 9, rem = l % 9, bb = rem / 3, cc = rem % 3;
    const int sf = f + a - 1, sy = y + bb - 1, sx = xx + cc - 1;
    if (l < 27 && (unsigned)sf < 8u && (unsigned)sy < 32u && (unsigned)sx < 32u) {
      const int tk = (sf << 10) | (sy << 5) | sx;
      if (tk <= i) my_nbr = tk;                     // causal
    }
  }

  // q fragment: head h = l>>3, dims e*8..e*8+7  (scale folded into w_q)
  const size_t qrow = (size_t)(i + 1) * QKV_COLS;
  float qf[8];
  {
    const u16x8 q8 = *(const u16x8*)(qkv + qrow + l * 8);
#pragma unroll
    for (int u = 0; u < 8; ++u) qf[u] = bf2f(q8[u]);
  }

  // ---- sim: s[p] = sim[h][8p+e] ----
  float s[4] = {-1e30f, -1e30f, -1e30f, -1e30f};
  {  // j = 0: BOS, row 0, never masked
    const u16x8 k8 = *(const u16x8*)(qkv + INNER + l * 8);
    float p = 0.f;
#pragma unroll
    for (int u = 0; u < 8; ++u) p = fmaf(qf[u], bf2f(k8[u]), p);
    p += __shfl_xor(p, 1); p += __shfl_xor(p, 2); p += __shfl_xor(p, 4);
    if (e == 0) s[0] = p;
  }
#pragma unroll
  for (int j = 1; j < 28; ++j) {
    const int tok = __shfl(my_nbr, j - 1);          // wave-uniform
    if (tok >= 0) {
      const u16x8 k8 = *(const u16x8*)(qkv + (size_t)(tok + 1) * QKV_COLS + INNER + l * 8);
      float p = 0.f;
#pragma unroll
      for (int u = 0; u < 8; ++u) p = fmaf(qf[u], bf2f(k8[u]), p);
      p += __shfl_xor(p, 1); p += __shfl_xor(p, 2); p += __shfl_xor(p, 4);
      if (e == (j & 7)) s[j >> 3] = p;
    }
  }

  // ---- softmax over 28 entries spread across 8 lanes x 4 regs ----
  float mx = fmaxf(fmaxf(s[0], s[1]), fmaxf(s[2], s[3]));
  mx = fmaxf(mx, __shfl_xor(mx, 1));
  mx = fmaxf(mx, __shfl_xor(mx, 2));
  mx = fmaxf(mx, __shfl_xor(mx, 4));
  float a4[4]; float sum = 0.f;
#pragma unroll
  for (int p = 0; p < 4; ++p) { a4[p] = __expf(s[p] - mx); sum += a4[p]; }
  sum += __shfl_xor(sum, 1); sum += __shfl_xor(sum, 2); sum += __shfl_xor(sum, 4);
  const float inv = 1.0f / sum;
#pragma unroll
  for (int p = 0; p < 4; ++p) a4[p] *= inv;

  // ---- talking heads: m[p] = mixed[h][8p+e] = sum_h2 wth[h][h2]*attn[h2][8p+e] ----
  float wth[8];
  {
    const float4 w0 = *(const float4*)(w_th + gbase);
    const float4 w1 = *(const float4*)(w_th + gbase + 4);
    wth[0] = w0.x; wth[1] = w0.y; wth[2] = w0.z; wth[3] = w0.w;
    wth[4] = w1.x; wth[5] = w1.y; wth[6] = w1.z; wth[7] = w1.w;
  }
  float m4[4];
#pragma unroll
  for (int p = 0; p < 4; ++p) {
    float acc = 0.f;
#pragma unroll
    for (int h2 = 0; h2 < 8; ++h2)
      acc = fmaf(wth[h2], __shfl(a4[p], (h2 << 3) | e), acc);
    m4[p] = acc;
  }

  // ---- PV: acc8[u] = out[h][e*8+u] ----
  float acc8[8] = {0.f, 0.f, 0.f, 0.f, 0.f, 0.f, 0.f, 0.f};
  {  // BOS
    const float mv = __shfl(m4[0], gbase);
    const u16x8 v8 = *(const u16x8*)(qkv + 2 * INNER + l * 8);
#pragma unroll
    for (int u = 0; u < 8; ++u) acc8[u] = fmaf(mv, bf2f(v8[u]), acc8[u]);
  }
#pragma unroll
  for (int j = 1; j < 28; ++j) {
    const int tok = __shfl(my_nbr, j - 1);
    if (tok >= 0) {
      const float mv = __shfl(m4[j >> 3], gbase | (j & 7));
      const u16x8 v8 = *(const u16x8*)(qkv + (size_t)(tok + 1) * QKV_COLS + 2 * INNER + l * 8);
#pragma unroll
      for (int u = 0; u < 8; ++u) acc8[u] = fmaf(mv, bf2f(v8[u]), acc8[u]);
    }
  }

  // store 16B coalesced
  u16x8 o;
#pragma unroll
  for (int u = 0; u < 8; ++u) o[u] = f2bf(acc8[u]);
  *(u16x8*)(Ob + (size_t)(i + 1) * INNER + l * 8) = o;
}

// ---------- BOS output row: O[0] = v[token0] ----------
__global__ void k_bos(const unsigned short* __restrict__ qkv, unsigned short* __restrict__ Ob) {
  const int t = (int)(blockIdx.x * 256 + threadIdx.x);
  if (t < INNER) Ob[t] = qkv[2 * INNER + t];
}

extern "C" void kernel_launch(void* const* d_in, const int* in_sizes, int n_in,
                              void* d_out, int out_size, void* d_ws, size_t ws_size,
                              hipStream_t stream) {
  (void)in_sizes; (void)n_in; (void)out_size; (void)ws_size;
  const float* x     = (const float*)d_in[0];
  const float* w_q   = (const float*)d_in[1];
  const float* w_kv  = (const float*)d_in[2];
  const float* w_th  = (const float*)d_in[3];
  const float* w_out = (const float*)d_in[4];
  const float* b_out = (const float*)d_in[5];
  float* out = (float*)d_out;

  char* ws = (char*)d_ws;
  unsigned short* xb    = (unsigned short*)ws;                       // MPAD*512 bf16 (reused as Ob)
  unsigned short* wqkvT = (unsigned short*)(ws + 8519680);           // 1536*512 bf16
  unsigned short* woutT = (unsigned short*)(ws + 8519680 + 1572864); // 512*512 bf16
  unsigned short* qkvb  = (unsigned short*)(ws + 8519680 + 1572864 + 524288); // 8193*1536 bf16

  // 1) fused conversions
  k_conv<<<CONV_TOT / 256, 256, 0, stream>>>(x, w_q, w_kv, w_out, xb, wqkvT, woutT);
  // 2) qkv = xb @ [w_q*0.125 | w_kv]
  k_gemm<QKV_COLS, true><<<dim3(MPAD / 128, QKV_COLS / 128), 256, 0, stream>>>(
      xb, wqkvT, qkvb, nullptr, NSEQ);
  // 3) sparse attention: one wave per token (writes Ob rows 1..8192; Ob aliases xb)
  k_attn2<<<NTOK / 4, 256, 0, stream>>>(qkvb, w_th, xb);
  k_bos<<<2, 256, 0, stream>>>(qkvb, xb);
  // 4) out = Ob @ w_out + b_out
  k_gemm<DIMC, false><<<dim3(MPAD / 128, DIMC / 128), 256, 0, stream>>>(
      xb, woutT, out, b_out, NSEQ);
}